// Round 8
// baseline (656.163 us; speedup 1.0000x reference)
//
#include <hip/hip_runtime.h>
#include <cstdint>
#include <cmath>

using short8  = __attribute__((ext_vector_type(8))) short;
using short4v = __attribute__((ext_vector_type(4))) short;
using floatx4 = __attribute__((ext_vector_type(4))) float;

__device__ __forceinline__ short f2bf(float f) {
  union { float f; unsigned u; } x; x.f = f;
  unsigned r = x.u + 0x7FFFu + ((x.u >> 16) & 1u);
  return (short)(r >> 16);
}

__device__ __forceinline__ float bf2f(short s) {
  union { unsigned u; float f; } x; x.u = ((unsigned)(unsigned short)s) << 16;
  return x.f;
}

__device__ __forceinline__ void gl_lds16(const short* g, short* l) {
  __builtin_amdgcn_global_load_lds(
      (const __attribute__((address_space(1))) void*)g,
      (__attribute__((address_space(3))) void*)l, 16, 0, 0);
}

#define NBLK 720

// r12 barrier: release = one device-scope fetch_add per block (~1-2us for
// 720 same-address adds at the L2 ordering point). Poll = device-scope
// atomic LOAD (no RMW — r11's atomicAdd(cnt,0) poll serialized against the
// release queue and cost ~80us/barrier; counters showed 250/292us idle).
__device__ __forceinline__ void grid_barrier(unsigned* cnt) {
  __syncthreads();
  if (threadIdx.x == 0) {
    __threadfence();
    __hip_atomic_fetch_add(cnt, 1u, __ATOMIC_ACQ_REL, __HIP_MEMORY_SCOPE_AGENT);
    while (__hip_atomic_load(cnt, __ATOMIC_ACQUIRE, __HIP_MEMORY_SCOPE_AGENT)
           < (unsigned)NBLK)
      __builtin_amdgcn_s_sleep(4);
    __threadfence();
  }
  __syncthreads();
}

// ===========================================================================
// r12 mega-kernel: identical to r11 (correctness-verified, absmax 0.0625)
// except the scalable barrier. prep -> conv_k3 -> kconv2 -> attn.
// ===========================================================================
__global__ __launch_bounds__(256, 3) void mega_kernel(
    const float* __restrict__ queries, const float* __restrict__ keys,
    const float* __restrict__ prior,
    const float* __restrict__ kw1, const float* __restrict__ kb1,
    const float* __restrict__ kw2, const float* __restrict__ kb2,
    const float* __restrict__ qw1, const float* __restrict__ qb1,
    const float* __restrict__ qw2, const float* __restrict__ qb2,
    const float* __restrict__ qw3, const float* __restrict__ qb3,
    short* __restrict__ kT0, short* __restrict__ qT0,
    short* __restrict__ w1, short* __restrict__ w2, short* __restrict__ w3,
    short* __restrict__ w4, short* __restrict__ w5,
    short* __restrict__ kT1, short* __restrict__ kF, short* __restrict__ qF,
    float* __restrict__ k2g, unsigned* __restrict__ cnt,
    float* __restrict__ out)
{
  __shared__ __align__(16) short smem[25600];   // 51,200 B
  const int tid = threadIdx.x, bid = blockIdx.x;
  const int wid = tid >> 6, lane = tid & 63;
  const int q = lane >> 4, m = lane & 15;

  // ======================= P0: prep (1649 units strided) ==================
  {
    float* xs = (float*)smem;   // [32][65]
    for (int u = bid; u < 1649; u += NBLK) {
      if (u < 1136) {
        const float* src; short* dst; int CIN, T, CP, bx, by, b;
        if (u < 512) {
          src = keys; dst = kT0; CIN = 256; T = 200; CP = 256;
          bx = u & 3; by = (u >> 2) & 7; b = u >> 5;
        } else {
          int b2 = u - 512;
          src = queries; dst = qT0; CIN = 80; T = 800; CP = 96;
          bx = b2 % 13; by = (b2 / 13) % 3; b = b2 / 39;
        }
        const int t0 = bx * 64, ci0 = by * 32;
        for (int i = tid; i < 32 * 64; i += 256) {
          int row = i >> 6, col = i & 63;
          float v = 0.f;
          if (ci0 + row < CIN && t0 + col < T)
            v = src[((size_t)b * CIN + ci0 + row) * T + t0 + col];
          xs[row * 65 + col] = v;
        }
        __syncthreads();
        int t = tid >> 2, c8 = (tid & 3) * 8;
        if (t0 + t < T) {
          short8 o;
          #pragma unroll
          for (int j = 0; j < 8; ++j) o[j] = f2bf(xs[(c8 + j) * 65 + t]);
          *(short8*)&dst[((size_t)b * T + t0 + t) * CP + ci0 + c8] = o;
        }
        __syncthreads();   // protect xs reuse by next unit
      } else {
        int blk = u - 1136;
        const float* src; short* dst; int base;
        int CoP, CiP, Cout, CIN, K; bool isW1 = false;
        if      (blk < 384) { src=kw1; dst=w1; base=0;   CoP=512; CiP=256; Cout=512; CIN=256; K=3; isW1=true; }
        else if (blk < 432) { src=kw2; dst=w2; base=384; CoP=96;  CiP=512; Cout=80;  CIN=512; K=1; }
        else if (blk < 486) { src=qw1; dst=w3; base=432; CoP=192; CiP=96;  Cout=160; CIN=80;  K=3; }
        else if (blk < 504) { src=qw2; dst=w4; base=486; CoP=96;  CiP=192; Cout=80;  CIN=160; K=1; }
        else                { src=qw3; dst=w5; base=504; CoP=96;  CiP=96;  Cout=80;  CIN=80;  K=1; }
        int tot = K * CoP * CiP;
        int b0 = (blk - base) * 1024;
        for (int e = 0; e < 4; ++e) {
          int gi = b0 + e * 256 + tid;
          if (gi < tot) {
            int dk  = gi / (CoP * CiP);
            int rem = gi - dk * (CoP * CiP);
            int co  = rem / CiP, ci = rem - (rem / CiP) * CiP;
            float v = (co < Cout && ci < CIN) ? src[((size_t)co * CIN + ci) * K + dk] : 0.f;
            int idx = gi;
            if (isW1) idx = (((ci >> 5) * 3 + dk) * 512 + co) * 32 + (ci & 31);
            dst[idx] = f2bf(v);
          }
        }
      }
    }
  }
  grid_barrier(cnt + 0);

  // ======================= P2: conv_k3 (720 roles) ========================
  if (bid < 512) {
    const int bb = bid >> 5, co0 = ((bid >> 2) & 7) * 64, t0 = (bid & 3) * 64;
    const int wy = wid >> 1, wx = wid & 1;
    const int wv = tid >> 6;

    floatx4 acc[2][2];
    #pragma unroll
    for (int i = 0; i < 2; ++i)
      #pragma unroll
      for (int j = 0; j < 2; ++j) acc[i][j] = (floatx4){0.f, 0.f, 0.f, 0.f};

    auto xload = [&](int c0s, int4& a, int4& bvv) {
      { int row = tid >> 2, g = tid & 3;
        int t = t0 + row - 1;
        a = (int4){0,0,0,0};
        if (t >= 0 && t < 200)
          a = *(const int4*)&kT0[((size_t)bb * 200 + t) * 256 + c0s * 32 + g * 8]; }
      bvv = (int4){0,0,0,0};
      if (tid < 8) {
        int i1 = tid + 256, row = i1 >> 2, g = i1 & 3;
        int t = t0 + row - 1;
        if (t >= 0 && t < 200)
          bvv = *(const int4*)&kT0[((size_t)bb * 200 + t) * 256 + c0s * 32 + g * 8];
      }
    };
    auto xstore = [&](const int4& a, const int4& bvv, int xoff) {
      { int row = tid >> 2, g = tid & 3; *(int4*)&smem[xoff + row * 40 + g * 8] = a; }
      if (tid < 8) { int i1 = tid + 256, row = i1 >> 2, g = i1 & 3;
        *(int4*)&smem[xoff + row * 40 + g * 8] = bvv; }
    };
    auto wissue = [&](int c0s, int aoff) {
      #pragma unroll
      for (int c = 0; c < 3; ++c) {
        const short* g = w1 + ((size_t)(c0s * 3 + c) * 512 + co0) * 32 + tid * 8;
        gl_lds16(g, &smem[aoff + c * 2048 + wv * 512]);
      }
    };

    { int4 a, bvv; xload(0, a, bvv); wissue(0, 5280); xstore(a, bvv, 0); }
    __syncthreads();

    int cur = 0;
    for (int c0 = 0; c0 < 8; ++c0) {
      const int xo = cur ? 2640 : 0;
      const int ao = cur ? 11424 : 5280;
      int4 xa, xb;
      if (c0 < 7) {
        wissue(c0 + 1, cur ? 5280 : 11424);
        xload(c0 + 1, xa, xb);
      }
      #pragma unroll
      for (int dk = 0; dk < 3; ++dk) {
        short8 fa0 = *(const short8*)&smem[ao + dk * 2048 + (wy * 32 + m) * 32 + q * 8];
        short8 fa1 = *(const short8*)&smem[ao + dk * 2048 + (wy * 32 + 16 + m) * 32 + q * 8];
        #pragma unroll
        for (int j = 0; j < 2; ++j) {
          short8 fb = *(const short8*)&smem[xo + (wx * 32 + j * 16 + m + dk) * 40 + q * 8];
          acc[0][j] = __builtin_amdgcn_mfma_f32_16x16x32_bf16(fa0, fb, acc[0][j], 0, 0, 0);
          acc[1][j] = __builtin_amdgcn_mfma_f32_16x16x32_bf16(fa1, fb, acc[1][j], 0, 0, 0);
        }
      }
      if (c0 < 7) {
        xstore(xa, xb, cur ? 0 : 2640);
        __syncthreads();
      }
      cur ^= 1;
    }
    #pragma unroll
    for (int i = 0; i < 2; ++i) {
      #pragma unroll
      for (int j = 0; j < 2; ++j) {
        #pragma unroll
        for (int r = 0; r < 4; ++r) {
          int co = co0 + wy * 32 + i * 16 + q * 4 + r;
          int t  = t0 + wx * 32 + j * 16 + m;
          if (t < 200) {
            float v = fmaxf(acc[i][j][r] + kb1[co], 0.f);
            kT1[((size_t)bb * 200 + t) * 512 + co] = f2bf(v);
          }
        }
      }
    }
  } else {
    const int qbid = bid - 512;
    const int b = qbid / 13, t0 = (qbid % 13) * 64;
    short* xs2 = smem;            // [66][104] = 6864
    short* y1c = smem + 7680;     // [6][64][40] = 15360
    short* y2c = smem;            // [3][64][40] = 7680 (aliases xs2)

    floatx4 accq[3][4];
    #pragma unroll
    for (int f = 0; f < 3; ++f)
      #pragma unroll
      for (int tf = 0; tf < 4; ++tf) accq[f][tf] = (floatx4){0.f, 0.f, 0.f, 0.f};

    for (int i = tid; i < 66 * 12; i += 256) {
      int row = i / 12, g = i - (i / 12) * 12;
      int t = t0 + row - 1;
      int4 v = {0, 0, 0, 0};
      if (t >= 0 && t < 800)
        v = *(const int4*)&qT0[((size_t)b * 800 + t) * 96 + g * 8];
      *(int4*)&xs2[row * 104 + g * 8] = v;
    }
    __syncthreads();

    for (int c0 = 0; c0 < 3; ++c0) {
      #pragma unroll
      for (int dk = 0; dk < 3; ++dk) {
        short8 fa[3];
        #pragma unroll
        for (int f = 0; f < 3; ++f)
          fa[f] = *(const short8*)&w3[((size_t)(dk * 192 + wid * 48 + f * 16 + m)) * 96
                                      + c0 * 32 + q * 8];
        #pragma unroll
        for (int tf = 0; tf < 4; ++tf) {
          short8 fb = *(const short8*)&xs2[(tf * 16 + m + dk) * 104 + c0 * 32 + q * 8];
          #pragma unroll
          for (int f = 0; f < 3; ++f)
            accq[f][tf] = __builtin_amdgcn_mfma_f32_16x16x32_bf16(fa[f], fb, accq[f][tf], 0, 0, 0);
        }
      }
    }
    __syncthreads();
    #pragma unroll
    for (int f = 0; f < 3; ++f) {
      #pragma unroll
      for (int tf = 0; tf < 4; ++tf) {
        int co = wid * 48 + f * 16 + q * 4;
        int t  = tf * 16 + m;
        short4v o;
        #pragma unroll
        for (int r = 0; r < 4; ++r) {
          float bv = (co + r < 160) ? qb1[co + r] : 0.f;
          o[r] = f2bf(fmaxf(accq[f][tf][r] + bv, 0.f));
        }
        *(short4v*)&y1c[(co >> 5) * 2560 + t * 40 + (co & 31)] = o;
      }
    }
    __syncthreads();

    floatx4 acc2q[6];
    #pragma unroll
    for (int f = 0; f < 6; ++f) acc2q[f] = (floatx4){0.f, 0.f, 0.f, 0.f};
    #pragma unroll
    for (int c = 0; c < 6; ++c) {
      short8 fb = *(const short8*)&y1c[c * 2560 + (wid * 16 + m) * 40 + q * 8];
      #pragma unroll
      for (int f = 0; f < 6; ++f) {
        short8 fa = *(const short8*)&w4[((size_t)(f * 16 + m)) * 192 + c * 32 + q * 8];
        acc2q[f] = __builtin_amdgcn_mfma_f32_16x16x32_bf16(fa, fb, acc2q[f], 0, 0, 0);
      }
    }
    #pragma unroll
    for (int f = 0; f < 6; ++f) {
      int co = f * 16 + q * 4;
      int t  = wid * 16 + m;
      short4v o;
      #pragma unroll
      for (int r = 0; r < 4; ++r) {
        float bv = (co + r < 80) ? qb2[co + r] : 0.f;
        o[r] = f2bf(fmaxf(acc2q[f][r] + bv, 0.f));
      }
      *(short4v*)&y2c[(co >> 5) * 2560 + t * 40 + (co & 31)] = o;
    }
    __syncthreads();

    floatx4 acc3q[6];
    #pragma unroll
    for (int f = 0; f < 6; ++f) acc3q[f] = (floatx4){0.f, 0.f, 0.f, 0.f};
    #pragma unroll
    for (int c = 0; c < 3; ++c) {
      short8 fb = *(const short8*)&y2c[c * 2560 + (wid * 16 + m) * 40 + q * 8];
      #pragma unroll
      for (int f = 0; f < 6; ++f) {
        short8 fa = *(const short8*)&w5[((size_t)(f * 16 + m)) * 96 + c * 32 + q * 8];
        acc3q[f] = __builtin_amdgcn_mfma_f32_16x16x32_bf16(fa, fb, acc3q[f], 0, 0, 0);
      }
    }
    int t = t0 + wid * 16 + m;
    if (t < 800) {
      #pragma unroll
      for (int f = 0; f < 6; ++f) {
        int co = f * 16 + q * 4;
        short4v o;
        #pragma unroll
        for (int r = 0; r < 4; ++r) {
          float bv = (co + r < 80) ? qb3[co + r] : 0.f;
          o[r] = f2bf(acc3q[f][r] + bv);
        }
        *(short4v*)&qF[((size_t)b * 800 + t) * 96 + co] = o;
      }
    }
  }
  grid_barrier(cnt + 1);

  // ======================= P4: kconv2 (208 wave tasks) ====================
  {
    int w = bid * 4 + wid;
    if (w < 208) {
      const int b = w / 13, t0 = (w - b * 13) * 16;
      const int t = t0 + m;
      const bool tv = (t < 200);

      floatx4 acc[6];
      #pragma unroll
      for (int f = 0; f < 6; ++f) acc[f] = (floatx4){0.f, 0.f, 0.f, 0.f};

      #pragma unroll
      for (int c = 0; c < 16; ++c) {
        short8 fb;
        if (tv) fb = *(const short8*)&kT1[((size_t)b * 200 + t) * 512 + c * 32 + q * 8];
        else    fb = (short8){0,0,0,0,0,0,0,0};
        #pragma unroll
        for (int f = 0; f < 6; ++f) {
          short8 fa = *(const short8*)&w2[((size_t)(f * 16 + m)) * 512 + c * 32 + q * 8];
          acc[f] = __builtin_amdgcn_mfma_f32_16x16x32_bf16(fa, fb, acc[f], 0, 0, 0);
        }
      }
      if (tv) {
        float k2acc = 0.f;
        #pragma unroll
        for (int f = 0; f < 6; ++f) {
          int co = f * 16 + q * 4;
          short4v o;
          #pragma unroll
          for (int r = 0; r < 4; ++r) {
            float bv = (co + r < 80) ? kb2[co + r] : 0.f;
            short s = f2bf(acc[f][r] + bv);
            o[r] = s;
            float vb = bf2f(s);
            k2acc = fmaf(vb, vb, k2acc);
          }
          *(short4v*)&kF[((size_t)b * 200 + t) * 96 + co] = o;
        }
        k2acc += __shfl_xor(k2acc, 16);
        k2acc += __shfl_xor(k2acc, 32);
        if (q == 0) k2g[b * 200 + t] = k2acc;
      }
    }
  }
  grid_barrier(cnt + 2);

  // ======================= P6: attn (400 half-block tasks) ================
  if (bid < 200) {
    const int half = tid >> 7, htid = tid & 127;
    const int hwid = htid >> 6;        // 0..1
    const int hl = htid & 63;
    const int hq = hl >> 4, hm = hl & 15;
    const int tile = bid * 2 + half;   // 0..399
    const int b = tile / 25, t1_0 = (tile % 25) * 32;

    short* aq = smem + half * 12800;           // 32*104 shorts
    short* bk = smem + half * 12800 + 3328;    // 208*40 shorts
    float* sstage = (float*)(smem + half * 12800);  // 32*200 floats

    floatx4 acc[13];
    #pragma unroll
    for (int f = 0; f < 13; ++f) acc[f] = (floatx4){0.f, 0.f, 0.f, 0.f};

    for (int i = htid; i < 32 * 12; i += 128) {
      int row = i / 12, g = i - (i / 12) * 12;
      *(int4*)&aq[row * 104 + g * 8] =
          *(const int4*)&qF[((size_t)b * 800 + t1_0 + row) * 96 + g * 8];
    }

    for (int c = 0; c < 3; ++c) {
      __syncthreads();
      for (int i = htid; i < 208 * 4; i += 128) {
        int row = i >> 2, g = i & 3;
        int4 v = {0, 0, 0, 0};
        if (row < 200)
          v = *(const int4*)&kF[((size_t)b * 200 + row) * 96 + c * 32 + g * 8];
        *(int4*)&bk[row * 40 + g * 8] = v;
      }
      __syncthreads();
      short8 fa = *(const short8*)&aq[(hwid * 16 + hm) * 104 + c * 32 + hq * 8];
      #pragma unroll
      for (int f = 0; f < 13; ++f) {
        short8 fb = *(const short8*)&bk[(f * 16 + hm) * 40 + hq * 8];
        acc[f] = __builtin_amdgcn_mfma_f32_16x16x32_bf16(fa, fb, acc[f], 0, 0, 0);
      }
    }

    float k2v[13];
    #pragma unroll
    for (int f = 0; f < 13; ++f) {
      int col = f * 16 + hm;
      k2v[f] = (col < 200) ? k2g[b * 200 + col] : 0.f;
    }

    float mx[4] = {-INFINITY, -INFINITY, -INFINITY, -INFINITY};
    #pragma unroll
    for (int f = 0; f < 13; ++f) {
      bool valid = (f * 16 + hm) < 200;
      #pragma unroll
      for (int r = 0; r < 4; ++r) {
        float v = valid ? (0.001f * acc[f][r] - 0.0005f * k2v[f]) : -INFINITY;
        acc[f][r] = v;
        mx[r] = fmaxf(mx[r], v);
      }
    }
    #pragma unroll
    for (int msk = 1; msk < 16; msk <<= 1)
      #pragma unroll
      for (int r = 0; r < 4; ++r) mx[r] = fmaxf(mx[r], __shfl_xor(mx[r], msk));
    float sm[4] = {0.f, 0.f, 0.f, 0.f};
    #pragma unroll
    for (int f = 0; f < 13; ++f)
      #pragma unroll
      for (int r = 0; r < 4; ++r) sm[r] += __expf(acc[f][r] - mx[r]);
    #pragma unroll
    for (int msk = 1; msk < 16; msk <<= 1)
      #pragma unroll
      for (int r = 0; r < 4; ++r) sm[r] += __shfl_xor(sm[r], msk);
    float lse[4];
    #pragma unroll
    for (int r = 0; r < 4; ++r) lse[r] = mx[r] + __logf(sm[r]);

    __syncthreads();
    #pragma unroll
    for (int f = 0; f < 13; ++f) {
      int col = f * 16 + hm;
      if (col < 200) {
        #pragma unroll
        for (int r = 0; r < 4; ++r)
          sstage[(hwid * 16 + hq * 4 + r) * 200 + col] = acc[f][r] - lse[r];
      }
    }
    __syncthreads();

    for (int i = htid; i < 32 * 50; i += 128) {
      int row = i / 50, seg = i - (i / 50) * 50;
      size_t o = ((size_t)b * 800 + t1_0 + row) * 200 + seg * 4;
      floatx4 pv = *(const floatx4*)&prior[o];
      floatx4 sv = *(const floatx4*)&sstage[row * 200 + seg * 4];
      floatx4 ov;
      #pragma unroll
      for (int j = 0; j < 4; ++j) ov[j] = sv[j] + __logf(pv[j] + 1e-8f);
      *(floatx4*)&out[o] = ov;
    }
  }
}

extern "C" void kernel_launch(void* const* d_in, const int* in_sizes, int n_in,
                              void* d_out, int out_size, void* d_ws, size_t ws_size,
                              hipStream_t stream) {
  const float* queries = (const float*)d_in[0];
  const float* keys    = (const float*)d_in[1];
  const float* prior   = (const float*)d_in[2];
  const float* kw1 = (const float*)d_in[3];
  const float* kb1 = (const float*)d_in[4];
  const float* kw2 = (const float*)d_in[5];
  const float* kb2 = (const float*)d_in[6];
  const float* qw1 = (const float*)d_in[7];
  const float* qb1 = (const float*)d_in[8];
  const float* qw2 = (const float*)d_in[9];
  const float* qb2 = (const float*)d_in[10];
  const float* qw3 = (const float*)d_in[11];
  const float* qb3 = (const float*)d_in[12];
  float* out = (float*)d_out;

  short* p = (short*)d_ws;
  short* kT0 = p;  p += (size_t)3200 * 256;
  short* qT0 = p;  p += (size_t)12800 * 96;
  short* w1  = p;  p += (size_t)3 * 512 * 256;
  short* w2  = p;  p += (size_t)96 * 512;
  short* w3  = p;  p += (size_t)3 * 192 * 96;
  short* w4  = p;  p += (size_t)96 * 192;
  short* w5  = p;  p += (size_t)96 * 96;
  short* kT1 = p;  p += (size_t)3200 * 512;
  short* kF  = p;  p += (size_t)3200 * 96;
  short* qF  = p;  p += (size_t)12800 * 96;
  float* k2g = (float*)p;              // 3200 floats
  unsigned* cnt = (unsigned*)(k2g + 3200);  // 3 barrier counters

  hipMemsetAsync(cnt, 0, 3 * sizeof(unsigned), stream);
  mega_kernel<<<dim3(NBLK), dim3(256), 0, stream>>>(
      queries, keys, prior, kw1, kb1, kw2, kb2,
      qw1, qb1, qw2, qb2, qw3, qb3,
      kT0, qT0, w1, w2, w3, w4, w5,
      kT1, kF, qF, k2g, cnt, out);
}

// Round 9
// 171.536 us; speedup vs baseline: 3.8252x; 3.8252x over previous
//
#include <hip/hip_runtime.h>
#include <cstdint>
#include <cmath>

using short8  = __attribute__((ext_vector_type(8))) short;
using short4v = __attribute__((ext_vector_type(4))) short;
using floatx4 = __attribute__((ext_vector_type(4))) float;

__device__ __forceinline__ short f2bf(float f) {
  union { float f; unsigned u; } x; x.f = f;
  unsigned r = x.u + 0x7FFFu + ((x.u >> 16) & 1u);
  return (short)(r >> 16);
}

__device__ __forceinline__ float bf2f(short s) {
  union { unsigned u; float f; } x; x.u = ((unsigned)(unsigned short)s) << 16;
  return x.f;
}

__device__ __forceinline__ void gl_lds16(const short* g, short* l) {
  __builtin_amdgcn_global_load_lds(
      (const __attribute__((address_space(1))) void*)g,
      (__attribute__((address_space(3))) void*)l, 16, 0, 0);
}

// ===========================================================================
// prep (r6-verified): cast/transpose keys+queries, pack 5 weights to bf16.
// w1 repacked to [c0(8)][dk(3)][co(512)][ci32] -> linear 4KB gl_lds chunks.
// ===========================================================================
__global__ __launch_bounds__(256) void prep_kernel(
    const float* __restrict__ keys, const float* __restrict__ queries,
    const float* __restrict__ kw1, const float* __restrict__ kw2,
    const float* __restrict__ qw1, const float* __restrict__ qw2,
    const float* __restrict__ qw3,
    short* __restrict__ kT0, short* __restrict__ qT0,
    short* __restrict__ w1, short* __restrict__ w2, short* __restrict__ w3,
    short* __restrict__ w4, short* __restrict__ w5)
{
  const int bid = blockIdx.x, tid = threadIdx.x;
  __shared__ float xs[32][65];

  if (bid < 1136) {
    const float* src; short* dst; int CIN, T, CP, bx, by, b;
    if (bid < 512) {
      src = keys; dst = kT0; CIN = 256; T = 200; CP = 256;
      bx = bid & 3; by = (bid >> 2) & 7; b = bid >> 5;
    } else {
      int b2 = bid - 512;
      src = queries; dst = qT0; CIN = 80; T = 800; CP = 96;
      bx = b2 % 13; by = (b2 / 13) % 3; b = b2 / 39;
    }
    const int t0 = bx * 64, ci0 = by * 32;
    for (int i = tid; i < 32 * 64; i += 256) {
      int row = i >> 6, col = i & 63;
      float v = 0.f;
      if (ci0 + row < CIN && t0 + col < T)
        v = src[((size_t)b * CIN + ci0 + row) * T + t0 + col];
      xs[row][col] = v;
    }
    __syncthreads();
    int t = tid >> 2, c8 = (tid & 3) * 8;
    if (t0 + t < T) {
      short8 o;
      #pragma unroll
      for (int j = 0; j < 8; ++j) o[j] = f2bf(xs[c8 + j][t]);
      *(short8*)&dst[((size_t)b * T + t0 + t) * CP + ci0 + c8] = o;
    }
  } else {
    int blk = bid - 1136;
    const float* src; short* dst; int base;
    int CoP, CiP, Cout, CIN, K; bool isW1 = false;
    if      (blk < 384) { src=kw1; dst=w1; base=0;   CoP=512; CiP=256; Cout=512; CIN=256; K=3; isW1=true; }
    else if (blk < 432) { src=kw2; dst=w2; base=384; CoP=96;  CiP=512; Cout=80;  CIN=512; K=1; }
    else if (blk < 486) { src=qw1; dst=w3; base=432; CoP=192; CiP=96;  Cout=160; CIN=80;  K=3; }
    else if (blk < 504) { src=qw2; dst=w4; base=486; CoP=96;  CiP=192; Cout=80;  CIN=160; K=1; }
    else                { src=qw3; dst=w5; base=504; CoP=96;  CiP=96;  Cout=80;  CIN=80;  K=1; }
    int tot = K * CoP * CiP;
    int b0 = (blk - base) * 1024;
    for (int e = 0; e < 4; ++e) {
      int gi = b0 + e * 256 + tid;
      if (gi < tot) {
        int dk  = gi / (CoP * CiP);
        int rem = gi - dk * (CoP * CiP);
        int co  = rem / CiP, ci = rem - (rem / CiP) * CiP;
        float v = (co < Cout && ci < CIN) ? src[((size_t)co * CIN + ci) * K + dk] : 0.f;
        int idx = gi;
        if (isW1) idx = (((ci >> 5) * 3 + dk) * 512 + co) * 32 + (ci & 31);
        dst[idx] = f2bf(v);
      }
    }
  }
}

// ===========================================================================
// conv_k3 (r8-verified): key conv1 with x-slice dbuf + gl_lds weight dbuf,
// 1 barrier/c0, 46,080 B LDS. Query chain with y2c aliasing dead xs2.
// ===========================================================================
__global__ __launch_bounds__(256) void conv_k3_kernel(
    const short* __restrict__ kT0, const short* __restrict__ qT0,
    const short* __restrict__ w1, const short* __restrict__ w3,
    const short* __restrict__ w4, const short* __restrict__ w5,
    const float* __restrict__ kb1, const float* __restrict__ qb1,
    const float* __restrict__ qb2, const float* __restrict__ qb3,
    short* __restrict__ kT1, short* __restrict__ qF)
{
  __shared__ __align__(16) short smem[23040];   // 46,080 B
  const int tid = threadIdx.x, wid = tid >> 6, lane = tid & 63;
  const int q = lane >> 4, m = lane & 15;

  if (blockIdx.x < 512) {
    const int blk = blockIdx.x;
    const int bb = blk >> 5, co0 = ((blk >> 2) & 7) * 64, t0 = (blk & 3) * 64;
    const int wy = wid >> 1, wx = wid & 1;
    const int wv = tid >> 6;

    floatx4 acc[2][2];
    #pragma unroll
    for (int i = 0; i < 2; ++i)
      #pragma unroll
      for (int j = 0; j < 2; ++j) acc[i][j] = (floatx4){0.f, 0.f, 0.f, 0.f};

    auto xload = [&](int c0s, int4& a, int4& bvv) {
      { int row = tid >> 2, g = tid & 3;
        int t = t0 + row - 1;
        a = (int4){0,0,0,0};
        if (t >= 0 && t < 200)
          a = *(const int4*)&kT0[((size_t)bb * 200 + t) * 256 + c0s * 32 + g * 8]; }
      bvv = (int4){0,0,0,0};
      if (tid < 8) {
        int i1 = tid + 256, row = i1 >> 2, g = i1 & 3;
        int t = t0 + row - 1;
        if (t >= 0 && t < 200)
          bvv = *(const int4*)&kT0[((size_t)bb * 200 + t) * 256 + c0s * 32 + g * 8];
      }
    };
    auto xstore = [&](const int4& a, const int4& bvv, int xoff) {
      { int row = tid >> 2, g = tid & 3; *(int4*)&smem[xoff + row * 40 + g * 8] = a; }
      if (tid < 8) { int i1 = tid + 256, row = i1 >> 2, g = i1 & 3;
        *(int4*)&smem[xoff + row * 40 + g * 8] = bvv; }
    };
    auto wissue = [&](int c0s, int aoff) {
      #pragma unroll
      for (int c = 0; c < 3; ++c) {
        const short* g = w1 + ((size_t)(c0s * 3 + c) * 512 + co0) * 32 + tid * 8;
        gl_lds16(g, &smem[aoff + c * 2048 + wv * 512]);
      }
    };

    { int4 a, bvv; xload(0, a, bvv); wissue(0, 5280); xstore(a, bvv, 0); }
    __syncthreads();

    int cur = 0;
    for (int c0 = 0; c0 < 8; ++c0) {
      const int xo = cur ? 2640 : 0;
      const int ao = cur ? 11424 : 5280;
      int4 xa, xb;
      if (c0 < 7) {
        wissue(c0 + 1, cur ? 5280 : 11424);
        xload(c0 + 1, xa, xb);
      }
      #pragma unroll
      for (int dk = 0; dk < 3; ++dk) {
        short8 fa0 = *(const short8*)&smem[ao + dk * 2048 + (wy * 32 + m) * 32 + q * 8];
        short8 fa1 = *(const short8*)&smem[ao + dk * 2048 + (wy * 32 + 16 + m) * 32 + q * 8];
        #pragma unroll
        for (int j = 0; j < 2; ++j) {
          short8 fb = *(const short8*)&smem[xo + (wx * 32 + j * 16 + m + dk) * 40 + q * 8];
          acc[0][j] = __builtin_amdgcn_mfma_f32_16x16x32_bf16(fa0, fb, acc[0][j], 0, 0, 0);
          acc[1][j] = __builtin_amdgcn_mfma_f32_16x16x32_bf16(fa1, fb, acc[1][j], 0, 0, 0);
        }
      }
      if (c0 < 7) {
        xstore(xa, xb, cur ? 0 : 2640);
        __syncthreads();
      }
      cur ^= 1;
    }
    #pragma unroll
    for (int i = 0; i < 2; ++i) {
      #pragma unroll
      for (int j = 0; j < 2; ++j) {
        #pragma unroll
        for (int r = 0; r < 4; ++r) {
          int co = co0 + wy * 32 + i * 16 + q * 4 + r;
          int t  = t0 + wx * 32 + j * 16 + m;
          if (t < 200) {
            float v = fmaxf(acc[i][j][r] + kb1[co], 0.f);
            kT1[((size_t)bb * 200 + t) * 512 + co] = f2bf(v);
          }
        }
      }
    }
  } else {
    const int qbid = blockIdx.x - 512;
    const int b = qbid / 13, t0 = (qbid % 13) * 64;
    short* xs2 = smem;            // [66][104] = 6864
    short* y1c = smem + 7680;     // [6][64][40] = 15360
    short* y2c = smem;            // [3][64][40] = 7680 (aliases xs2)

    floatx4 accq[3][4];
    #pragma unroll
    for (int f = 0; f < 3; ++f)
      #pragma unroll
      for (int tf = 0; tf < 4; ++tf) accq[f][tf] = (floatx4){0.f, 0.f, 0.f, 0.f};

    for (int i = tid; i < 66 * 12; i += 256) {
      int row = i / 12, g = i - (i / 12) * 12;
      int t = t0 + row - 1;
      int4 v = {0, 0, 0, 0};
      if (t >= 0 && t < 800)
        v = *(const int4*)&qT0[((size_t)b * 800 + t) * 96 + g * 8];
      *(int4*)&xs2[row * 104 + g * 8] = v;
    }
    __syncthreads();

    for (int c0 = 0; c0 < 3; ++c0) {
      #pragma unroll
      for (int dk = 0; dk < 3; ++dk) {
        short8 fa[3];
        #pragma unroll
        for (int f = 0; f < 3; ++f)
          fa[f] = *(const short8*)&w3[((size_t)(dk * 192 + wid * 48 + f * 16 + m)) * 96
                                      + c0 * 32 + q * 8];
        #pragma unroll
        for (int tf = 0; tf < 4; ++tf) {
          short8 fb = *(const short8*)&xs2[(tf * 16 + m + dk) * 104 + c0 * 32 + q * 8];
          #pragma unroll
          for (int f = 0; f < 3; ++f)
            accq[f][tf] = __builtin_amdgcn_mfma_f32_16x16x32_bf16(fa[f], fb, accq[f][tf], 0, 0, 0);
        }
      }
    }
    __syncthreads();
    #pragma unroll
    for (int f = 0; f < 3; ++f) {
      #pragma unroll
      for (int tf = 0; tf < 4; ++tf) {
        int co = wid * 48 + f * 16 + q * 4;
        int t  = tf * 16 + m;
        short4v o;
        #pragma unroll
        for (int r = 0; r < 4; ++r) {
          float bv = (co + r < 160) ? qb1[co + r] : 0.f;
          o[r] = f2bf(fmaxf(accq[f][tf][r] + bv, 0.f));
        }
        *(short4v*)&y1c[(co >> 5) * 2560 + t * 40 + (co & 31)] = o;
      }
    }
    __syncthreads();

    floatx4 acc2q[6];
    #pragma unroll
    for (int f = 0; f < 6; ++f) acc2q[f] = (floatx4){0.f, 0.f, 0.f, 0.f};
    #pragma unroll
    for (int c = 0; c < 6; ++c) {
      short8 fb = *(const short8*)&y1c[c * 2560 + (wid * 16 + m) * 40 + q * 8];
      #pragma unroll
      for (int f = 0; f < 6; ++f) {
        short8 fa = *(const short8*)&w4[((size_t)(f * 16 + m)) * 192 + c * 32 + q * 8];
        acc2q[f] = __builtin_amdgcn_mfma_f32_16x16x32_bf16(fa, fb, acc2q[f], 0, 0, 0);
      }
    }
    #pragma unroll
    for (int f = 0; f < 6; ++f) {
      int co = f * 16 + q * 4;
      int t  = wid * 16 + m;
      short4v o;
      #pragma unroll
      for (int r = 0; r < 4; ++r) {
        float bv = (co + r < 80) ? qb2[co + r] : 0.f;
        o[r] = f2bf(fmaxf(acc2q[f][r] + bv, 0.f));
      }
      *(short4v*)&y2c[(co >> 5) * 2560 + t * 40 + (co & 31)] = o;
    }
    __syncthreads();

    floatx4 acc3q[6];
    #pragma unroll
    for (int f = 0; f < 6; ++f) acc3q[f] = (floatx4){0.f, 0.f, 0.f, 0.f};
    #pragma unroll
    for (int c = 0; c < 3; ++c) {
      short8 fb = *(const short8*)&y2c[c * 2560 + (wid * 16 + m) * 40 + q * 8];
      #pragma unroll
      for (int f = 0; f < 6; ++f) {
        short8 fa = *(const short8*)&w5[((size_t)(f * 16 + m)) * 96 + c * 32 + q * 8];
        acc3q[f] = __builtin_amdgcn_mfma_f32_16x16x32_bf16(fa, fb, acc3q[f], 0, 0, 0);
      }
    }
    int t = t0 + wid * 16 + m;
    if (t < 800) {
      #pragma unroll
      for (int f = 0; f < 6; ++f) {
        int co = f * 16 + q * 4;
        short4v o;
        #pragma unroll
        for (int r = 0; r < 4; ++r) {
          float bv = (co + r < 80) ? qb3[co + r] : 0.f;
          o[r] = f2bf(acc3q[f][r] + bv);
        }
        *(short4v*)&qF[((size_t)b * 800 + t) * 96 + co] = o;
      }
    }
  }
}

// ===========================================================================
// attn_fused (r13): r5-verified 64-row attn body + kconv2's kF GEMM computed
// IN-BLOCK into LDS (13x redundant per batch, +3.4 GF aggregate — cheap)
// instead of a separate dispatch. Deletes kconv2 kernel + kF/k2g round-trip.
// kFl [208][104] bf16 (rows 200..207 and cols 80..95 zero); k2 from kFl.
// ===========================================================================
__global__ __launch_bounds__(256) void attn_fused(
    const short* __restrict__ qT, const short* __restrict__ kT1,
    const short* __restrict__ w2, const float* __restrict__ kb2,
    const float* __restrict__ prior, float* __restrict__ out)
{
  const int b = blockIdx.y, t1_0 = blockIdx.x * 64;
  const int tid = threadIdx.x, wid = tid >> 6, lane = tid & 63;
  const int q = lane >> 4, m = lane & 15;

  // phase 1: kFl [208][104]s @0 (43264B), aq [64][104]s @43264 (13312B),
  //          k2s [208]f @56576 (832B) -> 57408B
  // phase 2: sstage [64][200]f @0 (51200B)
  __shared__ __align__(16) char smem[57408];
  short* kFl = (short*)smem;
  short* aq  = (short*)(smem + 43264);
  float* k2s = (float*)(smem + 56576);
  float* sstage = (float*)smem;

  // zero pad rows 200..207 (t2 tail)
  for (int i = tid; i < 8 * 13; i += 256) {
    int row = 200 + i / 13, g = i - (i / 13) * 13;
    *(int4*)&kFl[row * 104 + g * 8] = (int4){0, 0, 0, 0};
  }
  // stage aq (q-rows)
  for (int i = tid; i < 64 * 12; i += 256) {
    int row = i / 12, g = i - (i / 12) * 12;
    int4 v = {0, 0, 0, 0};
    if (t1_0 + row < 800)
      v = *(const int4*)&qT[((size_t)b * 800 + t1_0 + row) * 96 + g * 8];
    *(int4*)&aq[row * 104 + g * 8] = v;
  }

  // ---- kF = kT1 x w2 (+kb2), bf16-rounded, into kFl (kconv2-verified map:
  // col=m -> t2, row=q*4+r -> co). 13 groups of 16 t2 rows over 4 waves. ----
  for (int gi = 0; gi < 4; ++gi) {
    int g = wid + gi * 4;
    if (g > 12) break;          // wave-uniform
    int t2 = g * 16 + m;
    bool tv = (t2 < 200);

    floatx4 acc6[6];
    #pragma unroll
    for (int f = 0; f < 6; ++f) acc6[f] = (floatx4){0.f, 0.f, 0.f, 0.f};
    #pragma unroll
    for (int c = 0; c < 16; ++c) {
      short8 fb;
      if (tv) fb = *(const short8*)&kT1[((size_t)b * 200 + t2) * 512 + c * 32 + q * 8];
      else    fb = (short8){0,0,0,0,0,0,0,0};
      #pragma unroll
      for (int f = 0; f < 6; ++f) {
        short8 fa = *(const short8*)&w2[((size_t)(f * 16 + m)) * 512 + c * 32 + q * 8];
        acc6[f] = __builtin_amdgcn_mfma_f32_16x16x32_bf16(fa, fb, acc6[f], 0, 0, 0);
      }
    }
    if (tv) {
      #pragma unroll
      for (int f = 0; f < 6; ++f) {
        int co = f * 16 + q * 4;
        short4v o;
        #pragma unroll
        for (int r = 0; r < 4; ++r) {
          float bv = (co + r < 80) ? kb2[co + r] : 0.f;
          o[r] = f2bf(acc6[f][r] + bv);
        }
        *(short4v*)&kFl[t2 * 104 + co] = o;
      }
    }
  }
  __syncthreads();

  // ---- S = q.kF^T over 96-ch (3 slices), no restaging barriers ----
  floatx4 acc[13];
  #pragma unroll
  for (int f = 0; f < 13; ++f) acc[f] = (floatx4){0.f, 0.f, 0.f, 0.f};
  #pragma unroll
  for (int c = 0; c < 3; ++c) {
    short8 fa = *(const short8*)&aq[(wid * 16 + m) * 104 + c * 32 + q * 8];
    #pragma unroll
    for (int f = 0; f < 13; ++f) {
      short8 fb = *(const short8*)&kFl[(f * 16 + m) * 104 + c * 32 + q * 8];
      acc[f] = __builtin_amdgcn_mfma_f32_16x16x32_bf16(fa, fb, acc[f], 0, 0, 0);
    }
  }
  // ---- k2 from kFl (rounded bf16 values — numerics identical to r5) ----
  if (tid < 208) {
    float k2acc = 0.f;
    #pragma unroll
    for (int g = 0; g < 12; ++g) {
      short8 s = *(const short8*)&kFl[tid * 104 + g * 8];
      #pragma unroll
      for (int j = 0; j < 8; ++j) {
        float v = bf2f(s[j]);
        k2acc = fmaf(v, v, k2acc);
      }
    }
    k2s[tid] = k2acc;
  }
  __syncthreads();

  float k2v[13];
  #pragma unroll
  for (int f = 0; f < 13; ++f) k2v[f] = k2s[f * 16 + m];

  float mx[4] = {-INFINITY, -INFINITY, -INFINITY, -INFINITY};
  #pragma unroll
  for (int f = 0; f < 13; ++f) {
    bool valid = (f * 16 + m) < 200;
    #pragma unroll
    for (int r = 0; r < 4; ++r) {
      float v = valid ? (0.001f * acc[f][r] - 0.0005f * k2v[f]) : -INFINITY;
      acc[f][r] = v;
      mx[r] = fmaxf(mx[r], v);
    }
  }
  #pragma unroll
  for (int msk = 1; msk < 16; msk <<= 1)
    #pragma unroll
    for (int r = 0; r < 4; ++r) mx[r] = fmaxf(mx[r], __shfl_xor(mx[r], msk));
  float sm[4] = {0.f, 0.f, 0.f, 0.f};
  #pragma unroll
  for (int f = 0; f < 13; ++f)
    #pragma unroll
    for (int r = 0; r < 4; ++r) sm[r] += __expf(acc[f][r] - mx[r]);
  #pragma unroll
  for (int msk = 1; msk < 16; msk <<= 1)
    #pragma unroll
    for (int r = 0; r < 4; ++r) sm[r] += __shfl_xor(sm[r], msk);
  float lse[4];
  #pragma unroll
  for (int r = 0; r < 4; ++r) lse[r] = mx[r] + __logf(sm[r]);

  // all kFl/aq/k2s reads done; reuse LDS as f32 stage
  __syncthreads();
  #pragma unroll
  for (int f = 0; f < 13; ++f) {
    int col = f * 16 + m;
    if (col < 200) {
      #pragma unroll
      for (int r = 0; r < 4; ++r)
        sstage[(wid * 16 + q * 4 + r) * 200 + col] = acc[f][r] - lse[r];
    }
  }
  __syncthreads();

  // coalesced float4 epilogue: 64 rows x 50 segments
  for (int i = tid; i < 64 * 50; i += 256) {
    int row = i / 50, seg = i - (i / 50) * 50;
    int t1 = t1_0 + row;
    if (t1 < 800) {
      size_t o = ((size_t)b * 800 + t1) * 200 + seg * 4;
      floatx4 pv = *(const floatx4*)&prior[o];
      floatx4 sv = *(const floatx4*)&sstage[row * 200 + seg * 4];
      floatx4 ov;
      #pragma unroll
      for (int j = 0; j < 4; ++j) ov[j] = sv[j] + __logf(pv[j] + 1e-8f);
      *(floatx4*)&out[o] = ov;
    }
  }
}

extern "C" void kernel_launch(void* const* d_in, const int* in_sizes, int n_in,
                              void* d_out, int out_size, void* d_ws, size_t ws_size,
                              hipStream_t stream) {
  const float* queries = (const float*)d_in[0];
  const float* keys    = (const float*)d_in[1];
  const float* prior   = (const float*)d_in[2];
  const float* kw1 = (const float*)d_in[3];
  const float* kb1 = (const float*)d_in[4];
  const float* kw2 = (const float*)d_in[5];
  const float* kb2 = (const float*)d_in[6];
  const float* qw1 = (const float*)d_in[7];
  const float* qb1 = (const float*)d_in[8];
  const float* qw2 = (const float*)d_in[9];
  const float* qb2 = (const float*)d_in[10];
  const float* qw3 = (const float*)d_in[11];
  const float* qb3 = (const float*)d_in[12];
  float* out = (float*)d_out;

  short* p = (short*)d_ws;
  short* kT0 = p;  p += (size_t)3200 * 256;
  short* qT0 = p;  p += (size_t)12800 * 96;
  short* w1  = p;  p += (size_t)3 * 512 * 256;
  short* w2  = p;  p += (size_t)96 * 512;
  short* w3  = p;  p += (size_t)3 * 192 * 96;
  short* w4  = p;  p += (size_t)96 * 192;
  short* w5  = p;  p += (size_t)96 * 96;
  short* kT1 = p;  p += (size_t)3200 * 512;
  short* qF  = p;  p += (size_t)12800 * 96;

  prep_kernel<<<dim3(1649), 256, 0, stream>>>(keys, queries, kw1, kw2, qw1, qw2, qw3,
                                              kT0, qT0, w1, w2, w3, w4, w5);
  conv_k3_kernel<<<dim3(720), 256, 0, stream>>>(kT0, qT0, w1, w3, w4, w5,
                                                kb1, qb1, qb2, qb3, kT1, qF);
  attn_fused<<<dim3(13, 16), 256, 0, stream>>>(qF, kT1, w2, kb2, prior, out);
}